// Round 7
// baseline (186.284 us; speedup 1.0000x reference)
//
#include <hip/hip_runtime.h>
#include <hip/hip_bf16.h>
#include <hip/hip_fp16.h>
#include <math.h>

// Problem constants
#define B_ 4
#define C_ 256
#define H_ 64
#define W_ 64
#define COMP_ 64
#define K2_ 25
#define HW_ (H_*W_)   // 4096
#define EPS_ 1e-5f
#define WTE_STRIDE 26  // 25 k2 values padded to 26 for 8B-aligned float2 loads

typedef float v2f __attribute__((ext_vector_type(2)));
#define FMA2(a, b, c) __builtin_elementwise_fma((a), (b), (c))

// ---------------------------------------------------------------------------
// Kernel T: weight layout transforms (scalar-load-friendly).
//   wTc[c*64+o]                        = w_comp[o*256+c]
//   wTe[((o*9+q)*4+s2)*26 + k2]        = w_enc[((k2*4+s2)*64+o)*9+q]
// ---------------------------------------------------------------------------
__global__ void k_transpose(const float* __restrict__ w_comp,
                            const float* __restrict__ w_enc,
                            float* __restrict__ wTc,
                            float* __restrict__ wTe) {
    int t = blockIdx.x * 256 + threadIdx.x;
    if (t < COMP_ * C_) {
        int o = t & 63;
        int c = t >> 6;
        wTc[t] = w_comp[o * C_ + c];
    } else {
        int t2 = t - COMP_ * C_;
        if (t2 < 100 * COMP_ * 9) {
            int k2 = t2 % 25;
            int r = t2 / 25;
            int s2 = r & 3; r >>= 2;
            int q = r % 9;
            int o = r / 9;
            wTe[((o * 9 + q) * 4 + s2) * WTE_STRIDE + k2] =
                w_enc[(((k2 * 4 + s2) * COMP_) + o) * 9 + q];
        }
    }
}

// ---------------------------------------------------------------------------
// Kernel A: 1x1 compression (256->64) + BN + SiLU.
// grid (64 px-tiles, 2 ogH, B), block (64 px, 4 og, 2 cg) = 512 thr.
// 512 blocks -> 2 independent blocks/CU. Thread: 8 outputs over 128 ch;
// single-barrier 2-way LDS reduction (8 KB).
// ---------------------------------------------------------------------------
__global__ void __launch_bounds__(512)
k_compress(const float* __restrict__ x, const float* __restrict__ wTc,
           const float* __restrict__ gamma, const float* __restrict__ beta,
           const float* __restrict__ mean, const float* __restrict__ var,
           float* __restrict__ act) {
    __shared__ v2f red[16 * 64];                   // 8 KB
    const int tx = threadIdx.x;                    // px
    const int ty = threadIdx.y;                    // og (0..3)
    const int tz = threadIdx.z;                    // cg (0..1)
    const int ogu = __builtin_amdgcn_readfirstlane(ty);
    const int cgu = __builtin_amdgcn_readfirstlane(tz);
    const int ogH = blockIdx.y;                    // output half (0/1)
    const int b = blockIdx.z;
    const int p0 = blockIdx.x * 64;

    v2f acc2[4];
#pragma unroll
    for (int k = 0; k < 4; ++k) acc2[k] = (v2f){0.f, 0.f};

    const float* xb = x + (size_t)b * C_ * HW_ + p0 + tx;
#pragma unroll 8
    for (int cl = 0; cl < 128; ++cl) {
        int c = cgu * 128 + cl;                    // uniform
        float xv = xb[c * HW_];
        const v2f* w2 = (const v2f*)(wTc + c * COMP_ + ogH * 32 + ogu * 8);  // uniform
        v2f xv2 = (v2f){xv, xv};
#pragma unroll
        for (int k = 0; k < 4; ++k)
            acc2[k] = FMA2(xv2, w2[k], acc2[k]);
    }

    if (tz == 1) {
#pragma unroll
        for (int k = 0; k < 4; ++k) red[(ty * 4 + k) * 64 + tx] = acc2[k];
    }
    __syncthreads();
    if (tz == 0) {
#pragma unroll
        for (int k = 0; k < 4; ++k) {
            v2f s = acc2[k] + red[(ty * 4 + k) * 64 + tx];
            int o0 = ogH * 32 + ty * 8 + 2 * k;
#pragma unroll
            for (int h = 0; h < 2; ++h) {
                int o = o0 + h;
                float sv = (h == 0) ? s.x : s.y;
                float iv = gamma[o] * rsqrtf(var[o] + EPS_);
                float bn = (sv - mean[o]) * iv + beta[o];
                float sg = 1.f / (1.f + __expf(-bn));
                act[((b * COMP_ + o) * HW_) + p0 + tx] = bn * sg;
            }
        }
    }
}

// ---------------------------------------------------------------------------
// Kernel B: 3x3 encoder conv (64->100) + softmax(25) + fp16 transpose-out.
// grid (64 i, 2 sg, B) = 512 blocks -> 2/CU.  block (64 j, 2 s2sub, 4 og)
// = 512 thr.  s2 = sg*2+s2sub.  Thread: 25 logits over 16-ch quarter;
// single-barrier 3-buffer reduction; softmax in og0; fp16 transpose-out.
// ---------------------------------------------------------------------------
__global__ void __launch_bounds__(512)
k_encoder(const float* __restrict__ act, const float* __restrict__ wTe,
          __half* __restrict__ maskT) {
    __shared__ float sact[12672];                  // 50.7 KB (reused: bufs, st)
    const int tx = threadIdx.x;                    // j
    const int ty = threadIdx.y;                    // s2sub (0..1)
    const int tz = threadIdx.z;                    // og (0..3)
    const int tid = (tz * 2 + ty) * 64 + tx;
    const int i = blockIdx.x;
    const int sg = blockIdx.y;                     // s2 pair (0/1)
    const int b = blockIdx.z;
    const int s2u = sg * 2 + __builtin_amdgcn_readfirstlane(ty);
    const int ogu = __builtin_amdgcn_readfirstlane(tz);

    // stage act rows i-1..i+1 with zero halo: [row][o][col(=gj+1)], 3*64*66
    const float* ab = act + (size_t)b * COMP_ * HW_;
    for (int t = tid; t < 3 * COMP_ * 66; t += 512) {
        int col = t % 66;
        int r = t / 66;
        int o = r & 63;
        int row = r >> 6;
        int gi = i + row - 1;
        int gj = col - 1;
        float v = 0.f;
        if ((unsigned)gi < 64u && (unsigned)gj < 64u)
            v = ab[(o * H_ + gi) * W_ + gj];
        sact[t] = v;
    }
    __syncthreads();

    v2f acc2[13];
#pragma unroll
    for (int k = 0; k < 13; ++k) acc2[k] = (v2f){0.f, 0.f};

#pragma unroll 2
    for (int oi = 0; oi < 16; ++oi) {
        int o = ogu * 16 + oi;                     // uniform
#pragma unroll
        for (int q = 0; q < 9; ++q) {
            const int dy = q / 3, dx = q % 3;
            float a = sact[(dy * COMP_ + o) * 66 + tx + dx];
            const float* wb = wTe + ((o * 9 + q) * 4 + s2u) * WTE_STRIDE;  // uniform
            const v2f* w2 = (const v2f*)wb;
            v2f a2 = (v2f){a, a};
#pragma unroll
            for (int k = 0; k < 12; ++k)
                acc2[k] = FMA2(a2, w2[k], acc2[k]);
            acc2[12].x = fmaf(wb[24], a, acc2[12].x);
        }
    }
    __syncthreads();                               // sact reads done

    // single-barrier 3-buffer reduction: og 1..3 dump, og0 sums
    v2f* bufs = (v2f*)sact;                        // 3 bufs x 13*128 v2f
    const int rix = ty * 64 + tx;                  // 0..127
    if (tz != 0) {
#pragma unroll
        for (int k = 0; k < 13; ++k)
            bufs[(tz - 1) * 1664 + k * 128 + rix] = acc2[k];
    }
    __syncthreads();
    float ex[K2_];
    if (tz == 0) {
#pragma unroll
        for (int k = 0; k < 13; ++k)
            acc2[k] += bufs[k * 128 + rix] + bufs[1664 + k * 128 + rix] +
                       bufs[2 * 1664 + k * 128 + rix];

        // softmax over 25 (acc2[12].y is junk — ignored)
        float mx = acc2[12].x;
#pragma unroll
        for (int k = 0; k < 12; ++k) mx = fmaxf(mx, fmaxf(acc2[k].x, acc2[k].y));
        float sum = 0.f;
#pragma unroll
        for (int k = 0; k < 12; ++k) {
            ex[2 * k]     = __expf(acc2[k].x - mx);
            ex[2 * k + 1] = __expf(acc2[k].y - mx);
            sum += ex[2 * k] + ex[2 * k + 1];
        }
        ex[24] = __expf(acc2[12].x - mx);
        sum += ex[24];
        float rs = 1.f / sum;
#pragma unroll
        for (int k = 0; k < K2_; ++k) ex[k] *= rs;
    }
    __syncthreads();                               // buf reads done before reuse

    // fp16 transpose: st[j*100 + k2*4 + s2] for this block's two s2
    __half* st = (__half*)sact;
    if (tz == 0) {
#pragma unroll
        for (int k = 0; k < K2_; ++k)
            st[tx * 100 + k * 4 + sg * 2 + ty] = __float2half(ex[k]);
    }
    __syncthreads();

    // copy out owned dwords: maskT dword (i*64+j)*50 + k*2 + sg
    const unsigned* st32 = (const unsigned*)st;
    unsigned* dst = (unsigned*)(maskT + ((size_t)b * HW_ + i * 64) * 100);
    for (int e = tid; e < 1600; e += 512) {
        int j = e / 25, k = e - j * 25;
        dst[j * 50 + k * 2 + sg] = st32[j * 50 + k * 2 + sg];
    }
}

// ---------------------------------------------------------------------------
// Kernel C: reassembly + pixel shuffle, 32 channels/block.
// grid (64 i, 8 cc, B) = 2048 blocks -> 2/CU (61.8 KB LDS).
// block (64 j, 4 tq); tq owns 8 channels. Per k2: 2 ds_read_b128 (x) +
// 1 ds_read_b64 (fp16 mask) for 32 fma -> per-CU LDS ops halved vs R6.
// sx pad 36: 4*tx mod 32 bank starts -> conflict-free b128.
// ---------------------------------------------------------------------------
__global__ void __launch_bounds__(256)
k_reassemble(const float* __restrict__ x, const __half* __restrict__ maskT,
             float* __restrict__ out) {
    __shared__ __align__(16) __half smask[64 * 100];  // 12.8 KB
    __shared__ __align__(16) float sx[5 * 68 * 36];   // 48.96 KB
    const int tx = threadIdx.x;                    // j
    const int ty = threadIdx.y;                    // ch-octet (0..3)
    const int tid = ty * 64 + tx;
    const int i = blockIdx.x;
    const int cc = blockIdx.y;                     // 32-ch chunk (0..7)
    const int b = blockIdx.z;

    // ---- mask row: fully coalesced float4 copy (800 float4 of halfs) ----
    {
        const float4* src = (const float4*)(maskT + ((size_t)b * HW_ + i * 64) * 100);
        float4* dst = (float4*)smask;
#pragma unroll
        for (int t = 0; t < 4; ++t) {
            int e = tid + t * 256;
            if (e < 800) dst[e] = src[e];
        }
    }

    // ---- x tile: [r][col][ch pad36], staged via ds_write_b128 ----
    const float* xc0 = x + ((size_t)b * C_ + cc * 32) * HW_;
#pragma unroll
    for (int r = 0; r < 5; ++r) {
        const int gi = i + r - 2;                  // uniform
        const bool rowok = ((unsigned)gi < 64u);   // uniform branch
        {
            int gj = tx - 2;                       // -2..61
            float4 va = {0.f, 0.f, 0.f, 0.f};
            float4 vb = {0.f, 0.f, 0.f, 0.f};
            if (rowok && gj >= 0) {
                const float* p = xc0 + (ty * 8) * HW_ + gi * W_ + gj;
                va.x = p[0];        va.y = p[HW_];
                va.z = p[2 * HW_];  va.w = p[3 * HW_];
                vb.x = p[4 * HW_];  vb.y = p[5 * HW_];
                vb.z = p[6 * HW_];  vb.w = p[7 * HW_];
            }
            *(float4*)&sx[(r * 68 + tx) * 36 + ty * 8]     = va;
            *(float4*)&sx[(r * 68 + tx) * 36 + ty * 8 + 4] = vb;
        }
        if (tid < 32) {                            // tail cols 64..67, 8 ch-quads
            int quad = tid >> 2;                   // 0..7
            int col = 64 + (tid & 3);
            int gj = col - 2;                      // 62..65
            float4 v = {0.f, 0.f, 0.f, 0.f};
            if (rowok && gj < 64) {
                const float* p = xc0 + (quad * 4) * HW_ + gi * W_ + gj;
                v.x = p[0];       v.y = p[HW_];
                v.z = p[2 * HW_]; v.w = p[3 * HW_];
            }
            *(float4*)&sx[(r * 68 + col) * 36 + quad * 4] = v;
        }
    }
    __syncthreads();

    v2f a01[8], a23[8];
#pragma unroll
    for (int cl = 0; cl < 8; ++cl) { a01[cl] = (v2f){0.f, 0.f}; a23[cl] = (v2f){0.f, 0.f}; }

    // prefetch k2=0
    float4 xqA = *(const float4*)&sx[(0 * 68 + tx) * 36 + ty * 8];
    float4 xqB = *(const float4*)&sx[(0 * 68 + tx) * 36 + ty * 8 + 4];
    uint2 mu = *(const uint2*)&smask[tx * 100];

#pragma unroll
    for (int k2 = 0; k2 < K2_; ++k2) {
        float4 xA = xqA, xB = xqB;
        uint2 mc = mu;
        if (k2 < K2_ - 1) {
            const int kn = k2 + 1;
            const int dy = kn / 5, dx = kn % 5;
            xqA = *(const float4*)&sx[(dy * 68 + tx + dx) * 36 + ty * 8];
            xqB = *(const float4*)&sx[(dy * 68 + tx + dx) * 36 + ty * 8 + 4];
            mu  = *(const uint2*)&smask[tx * 100 + kn * 4];
        }
        float2 f01 = __half22float2(__builtin_bit_cast(__half2, mc.x));
        float2 f23 = __half22float2(__builtin_bit_cast(__half2, mc.y));
        v2f m01 = (v2f){f01.x, f01.y};
        v2f m23 = (v2f){f23.x, f23.y};
        float xcv[8] = {xA.x, xA.y, xA.z, xA.w, xB.x, xB.y, xB.z, xB.w};
#pragma unroll
        for (int cl = 0; cl < 8; ++cl) {
            v2f xv2 = (v2f){xcv[cl], xcv[cl]};
            a01[cl] = FMA2(xv2, m01, a01[cl]);
            a23[cl] = FMA2(xv2, m23, a23[cl]);
        }
    }

#pragma unroll
    for (int cl = 0; cl < 8; ++cl) {
        int c = cc * 32 + ty * 8 + cl;
        float* op = out + (((size_t)(b * C_ + c) * 128 + 2 * i) * 128) + 2 * tx;
        *(float2*)op         = float2{a01[cl].x, a01[cl].y};
        *(float2*)(op + 128) = float2{a23[cl].x, a23[cl].y};
    }
}

// ---------------------------------------------------------------------------
extern "C" void kernel_launch(void* const* d_in, const int* in_sizes, int n_in,
                              void* d_out, int out_size, void* d_ws, size_t ws_size,
                              hipStream_t stream) {
    const float* x       = (const float*)d_in[0];
    const float* w_comp  = (const float*)d_in[1];
    const float* bn_g    = (const float*)d_in[2];
    const float* bn_b    = (const float*)d_in[3];
    const float* bn_m    = (const float*)d_in[4];
    const float* bn_v    = (const float*)d_in[5];
    const float* w_enc   = (const float*)d_in[6];
    float* out = (float*)d_out;

    float* ws    = (float*)d_ws;
    float* wTc   = ws;                               // 16384 floats
    float* wTe   = ws + 16384;                       // 59904 floats (stride 26)
    float* act   = ws + 16384 + 59904;               // 1,048,576 floats
    __half* maskT = (__half*)(act + (size_t)B_ * COMP_ * HW_);  // 1,638,400 halfs

    k_transpose<<<289, 256, 0, stream>>>(w_comp, w_enc, wTc, wTe);
    k_compress<<<dim3(64, 2, B_), dim3(64, 4, 2), 0, stream>>>(x, wTc, bn_g, bn_b, bn_m, bn_v, act);
    k_encoder<<<dim3(64, 2, B_), dim3(64, 2, 4), 0, stream>>>(act, wTe, maskT);
    k_reassemble<<<dim3(64, 8, B_), dim3(64, 4), 0, stream>>>(x, maskT, out);
}